// Round 1
// baseline (398.351 us; speedup 1.0000x reference)
//
#include <hip/hip_runtime.h>
#include <hip/hip_bf16.h>

// Sizes (fixed for this problem)
// b=2, L=1024, d=1024, dt_rank=64, n=16, E=96
#define LSEQ 1024
#define DMODEL 1024
#define NSTATE 16
#define DTRANK 64
#define ECOL 96

// ---------------- Kernel A: x_dbl = x @ W_x  (2048 x 96, K=1024) ----------------
__global__ __launch_bounds__(384) void k_xdbl(const float* __restrict__ x,
                                              const float* __restrict__ Wx,
                                              float* __restrict__ xdbl) {
    __shared__ float xs[4][1024];
    int r0 = blockIdx.x * 4;
    int tid = threadIdx.y * 96 + threadIdx.x;  // 0..383
    for (int i = tid; i < 4 * 1024; i += 384) {
        int rr = i >> 10, kk = i & 1023;
        xs[rr][kk] = x[(size_t)(r0 + rr) * 1024 + kk];
    }
    __syncthreads();
    int e = threadIdx.x;   // 0..95
    int r = threadIdx.y;   // 0..3
    float acc = 0.f;
    for (int k = 0; k < 1024; k += 4) {
        acc += xs[r][k + 0] * Wx[(k + 0) * 96 + e];
        acc += xs[r][k + 1] * Wx[(k + 1) * 96 + e];
        acc += xs[r][k + 2] * Wx[(k + 2) * 96 + e];
        acc += xs[r][k + 3] * Wx[(k + 3) * 96 + e];
    }
    xdbl[(size_t)(r0 + r) * 96 + e] = acc;
}

// -------- Kernel B: delta = softplus(x_dbl[:, :64] @ W_dt + b_dt)  (2048 x 1024) --------
__global__ __launch_bounds__(256) void k_delta(const float* __restrict__ xdbl,
                                               const float* __restrict__ Wdt,
                                               const float* __restrict__ bdt,
                                               float* __restrict__ delta) {
    __shared__ float ds[32][64];
    int row0 = blockIdx.x * 32;
    int col0 = blockIdx.y * 256;
    int tid = threadIdx.x;
    for (int i = tid; i < 32 * 64; i += 256) {
        int rr = i >> 6, kk = i & 63;
        ds[rr][kk] = xdbl[(size_t)(row0 + rr) * 96 + kk];
    }
    __syncthreads();
    int c = col0 + tid;
    float acc[32];
#pragma unroll
    for (int r = 0; r < 32; ++r) acc[r] = 0.f;
    for (int k = 0; k < 64; ++k) {
        float w = Wdt[k * 1024 + c];
#pragma unroll
        for (int r = 0; r < 32; ++r) acc[r] += ds[r][k] * w;
    }
    float bb = bdt[c];
#pragma unroll
    for (int r = 0; r < 32; ++r) {
        float z = acc[r] + bb;
        // jax.nn.softplus = max(z,0) + log1p(exp(-|z|))
        float sp = fmaxf(z, 0.f) + log1pf(expf(-fabsf(z)));
        delta[(size_t)(row0 + r) * 1024 + c] = sp;
    }
}

// ---------------- Kernel C: selective scan -> y (2048 x 1024) ----------------
// Replicates reference formulation:
//   S[t] = sum_{j=t+1}^{L-1} dA[j],  dA[j] = delta[j,d]*A[d,n] = A * R[t] with
//   R[t] = suffix-sum of delta (double precision accumulation).
//   xs[t] = (sum_{s<=t} dBu[s]*e^{S[s]}) / (e^{S[t]} + 1e-12)
//   y[t,d] = sum_n xs*C[t,n] + u*D[d]
__global__ __launch_bounds__(256) void k_scan(const float* __restrict__ delta,
                                              const float* __restrict__ u,
                                              const float* __restrict__ xdbl,
                                              const float* __restrict__ Alog,
                                              const float* __restrict__ Dp,
                                              float* __restrict__ y) {
    __shared__ float sd[64][16];
    __shared__ float su[64][16];
    __shared__ float sb[64][16];
    __shared__ float sc[64][16];
    __shared__ float sy[64][16];
    __shared__ double red[16][17];
    __shared__ double totd[16];

    int b = blockIdx.x >> 6;            // 0..1
    int d0 = (blockIdx.x & 63) << 4;    // d tile of 16
    int tid = threadIdx.x;
    const size_t base_bd = (size_t)b * LSEQ * DMODEL;

    // Phase A: per-d total of delta over all t (double)
    {
        int dlA = tid & 15;
        int part = tid >> 4;
        double s = 0.0;
        for (int j = 0; j < 64; ++j) {
            int t = part * 64 + j;
            s += (double)delta[base_bd + (size_t)t * DMODEL + d0 + dlA];
        }
        red[part][dlA] = s;
    }
    __syncthreads();
    if (tid < 16) {
        double s = 0.0;
        for (int p = 0; p < 16; ++p) s += red[p][tid];
        totd[tid] = s;
    }
    __syncthreads();

    int dl = tid >> 4;   // 0..15 (d within tile)
    int n = tid & 15;    // 0..15 (state index)
    float Af = -expf(Alog[(d0 + dl) * NSTATE + n]);
    double Ad = (double)Af;
    double R = totd[dl];     // becomes suffix sum after first update
    float num = 0.f;

    for (int ch = 0; ch < 16; ++ch) {
        int t0 = ch * 64;
        __syncthreads();  // previous chunk's write phase done
        for (int i = tid; i < 64 * 16; i += 256) {
            int tt = i >> 4, dd = i & 15;
            size_t gt = base_bd + (size_t)(t0 + tt) * DMODEL + d0 + dd;
            sd[tt][dd] = delta[gt];
            su[tt][dd] = u[gt];
            int ei = ((b * LSEQ) + t0 + tt) * ECOL;
            sb[tt][dd] = xdbl[ei + DTRANK + dd];
            sc[tt][dd] = xdbl[ei + DTRANK + NSTATE + dd];
        }
        __syncthreads();
        for (int tt = 0; tt < 64; ++tt) {
            float dlt = sd[tt][dl];
            R -= (double)dlt;                       // R = suffix sum for this t
            float e = __expf((float)(Ad * R));      // e^{S[t]}
            float vv = dlt * su[tt][dl] * sb[tt][n] * e;
            num += vv;                              // forward cumsum (same order as ref)
            float xs = num / (e + 1e-12f);
            float yv = xs * sc[tt][n];
            yv += __shfl_xor(yv, 1);
            yv += __shfl_xor(yv, 2);
            yv += __shfl_xor(yv, 4);
            yv += __shfl_xor(yv, 8);
            if (n == 0) sy[tt][dl] = yv;
        }
        __syncthreads();
        for (int i = tid; i < 64 * 16; i += 256) {
            int tt = i >> 4, dd = i & 15;
            size_t gt = base_bd + (size_t)(t0 + tt) * DMODEL + d0 + dd;
            y[gt] = sy[tt][dd] + su[tt][dd] * Dp[d0 + dd];
        }
    }
}

// ---------------- Kernel D: out = y @ W_out + b_out  (2048 x 1024, K=1024) ----------------
__global__ __launch_bounds__(256) void k_out(const float* __restrict__ y,
                                             const float* __restrict__ W,
                                             const float* __restrict__ bias,
                                             float* __restrict__ out) {
    __shared__ float As[16][68];  // [k][m], padded row 68 floats (16B-aligned stride)
    __shared__ float Bs[16][68];  // [k][n]
    int bm = blockIdx.y * 64, bn = blockIdx.x * 64;
    int tid = threadIdx.x;
    int tx = tid & 15, ty = tid >> 4;
    float acc[4][4];
#pragma unroll
    for (int i = 0; i < 4; ++i)
#pragma unroll
        for (int j = 0; j < 4; ++j) acc[i][j] = 0.f;

    int lm = tid >> 2;          // 0..63  (A row)
    int lk4 = (tid & 3) * 4;    // 0,4,8,12 (A k group)
    int lk = tid >> 4;          // 0..15  (B k)
    int ln4 = (tid & 15) * 4;   // B col group

    for (int k0 = 0; k0 < 1024; k0 += 16) {
        float4 av = *reinterpret_cast<const float4*>(&y[(size_t)(bm + lm) * 1024 + k0 + lk4]);
        As[lk4 + 0][lm] = av.x;
        As[lk4 + 1][lm] = av.y;
        As[lk4 + 2][lm] = av.z;
        As[lk4 + 3][lm] = av.w;
        float4 bv = *reinterpret_cast<const float4*>(&W[(size_t)(k0 + lk) * 1024 + bn + ln4]);
        *reinterpret_cast<float4*>(&Bs[lk][ln4]) = bv;
        __syncthreads();
#pragma unroll
        for (int k = 0; k < 16; ++k) {
            float4 a = *reinterpret_cast<const float4*>(&As[k][ty * 4]);
            float4 bq = *reinterpret_cast<const float4*>(&Bs[k][tx * 4]);
            acc[0][0] += a.x * bq.x; acc[0][1] += a.x * bq.y; acc[0][2] += a.x * bq.z; acc[0][3] += a.x * bq.w;
            acc[1][0] += a.y * bq.x; acc[1][1] += a.y * bq.y; acc[1][2] += a.y * bq.z; acc[1][3] += a.y * bq.w;
            acc[2][0] += a.z * bq.x; acc[2][1] += a.z * bq.y; acc[2][2] += a.z * bq.z; acc[2][3] += a.z * bq.w;
            acc[3][0] += a.w * bq.x; acc[3][1] += a.w * bq.y; acc[3][2] += a.w * bq.z; acc[3][3] += a.w * bq.w;
        }
        __syncthreads();
    }
    float4 bb = *reinterpret_cast<const float4*>(&bias[bn + tx * 4]);
#pragma unroll
    for (int i = 0; i < 4; ++i) {
        float4 o;
        o.x = acc[i][0] + bb.x;
        o.y = acc[i][1] + bb.y;
        o.z = acc[i][2] + bb.z;
        o.w = acc[i][3] + bb.w;
        *reinterpret_cast<float4*>(&out[(size_t)(bm + ty * 4 + i) * 1024 + bn + tx * 4]) = o;
    }
}

extern "C" void kernel_launch(void* const* d_in, const int* in_sizes, int n_in,
                              void* d_out, int out_size, void* d_ws, size_t ws_size,
                              hipStream_t stream) {
    const float* x    = (const float*)d_in[0];
    const float* Wx   = (const float*)d_in[1];
    const float* Wdt  = (const float*)d_in[2];
    const float* bdt  = (const float*)d_in[3];
    const float* Alog = (const float*)d_in[4];
    const float* Dp   = (const float*)d_in[5];
    const float* Wout = (const float*)d_in[6];
    const float* bout = (const float*)d_in[7];
    float* out = (float*)d_out;

    float* xdbl  = (float*)d_ws;                      // 2048*96
    float* delta = xdbl + 2048 * 96;                  // 2048*1024
    float* yv    = delta + 2048 * 1024;               // 2048*1024

    k_xdbl<<<512, dim3(96, 4), 0, stream>>>(x, Wx, xdbl);
    k_delta<<<dim3(64, 4), 256, 0, stream>>>(xdbl, Wdt, bdt, delta);
    k_scan<<<128, 256, 0, stream>>>(delta, x, xdbl, Alog, Dp, yv);
    k_out<<<dim3(16, 32), 256, 0, stream>>>(yv, Wout, bout, out);
}

// Round 2
// 187.958 us; speedup vs baseline: 2.1194x; 2.1194x over previous
//
#include <hip/hip_runtime.h>
#include <hip/hip_bf16.h>

// b=2, L=1024, d=1024, dt_rank=64, n=16, E=96
#define LSEQ 1024
#define DMODEL 1024
#define NSTATE 16
#define DTRANK 64
#define ECOL 96
#define MTOT 2048

// ---------------- Kernel A: x_dbl = x @ W_x  (2048 x 96, K=1024) + packed BC ----------------
__global__ __launch_bounds__(384) void k_xdbl(const float* __restrict__ x,
                                              const float* __restrict__ Wx,
                                              float* __restrict__ xdbl,
                                              float2* __restrict__ bc) {
    __shared__ float xs[4][1024];
    __shared__ float sacc[4][96];
    int r0 = blockIdx.x * 4;
    int tid = threadIdx.y * 96 + threadIdx.x;  // 0..383
    for (int i = tid; i < 4 * 1024; i += 384) {
        int rr = i >> 10, kk = i & 1023;
        xs[rr][kk] = x[(size_t)(r0 + rr) * 1024 + kk];
    }
    __syncthreads();
    int e = threadIdx.x;   // 0..95
    int r = threadIdx.y;   // 0..3
    float acc = 0.f;
    for (int k = 0; k < 1024; k += 4) {
        acc += xs[r][k + 0] * Wx[(k + 0) * 96 + e];
        acc += xs[r][k + 1] * Wx[(k + 1) * 96 + e];
        acc += xs[r][k + 2] * Wx[(k + 2) * 96 + e];
        acc += xs[r][k + 3] * Wx[(k + 3) * 96 + e];
    }
    xdbl[(size_t)(r0 + r) * 96 + e] = acc;
    sacc[r][e] = acc;
    __syncthreads();
    if (tid < 64) {
        int rr = tid >> 4, n = tid & 15;
        bc[(size_t)(r0 + rr) * 16 + n] = make_float2(sacc[rr][64 + n], sacc[rr][80 + n]);
    }
}

// ---------------- Transpose x [2048][1024] -> xT [1024][2048] ----------------
__global__ __launch_bounds__(256) void k_transp(const float* __restrict__ in,
                                                float* __restrict__ out) {
    __shared__ float tile[32][33];
    int x0 = blockIdx.x * 32;  // d
    int y0 = blockIdx.y * 32;  // m
    int tx = threadIdx.x & 31, ty = threadIdx.x >> 5;  // ty 0..7
#pragma unroll
    for (int j = 0; j < 32; j += 8)
        tile[ty + j][tx] = in[(size_t)(y0 + ty + j) * 1024 + x0 + tx];
    __syncthreads();
#pragma unroll
    for (int j = 0; j < 32; j += 8)
        out[(size_t)(x0 + ty + j) * 2048 + y0 + tx] = tile[tx][ty + j];
}

// -------- Kernel B: deltaT[d][m] = softplus(x_dbl[:, :64] @ W_dt + b_dt)^T --------
__global__ __launch_bounds__(256) void k_delta(const float* __restrict__ xdbl,
                                               const float* __restrict__ Wdt,
                                               const float* __restrict__ bdt,
                                               float* __restrict__ deltaT) {
    __shared__ float ds[32][64];
    int row0 = blockIdx.x * 32;
    int col0 = blockIdx.y * 256;
    int tid = threadIdx.x;
    for (int i = tid; i < 32 * 64; i += 256) {
        int rr = i >> 6, kk = i & 63;
        ds[rr][kk] = xdbl[(size_t)(row0 + rr) * 96 + kk];
    }
    __syncthreads();
    int c = col0 + tid;  // d index
    float acc[32];
#pragma unroll
    for (int r = 0; r < 32; ++r) acc[r] = 0.f;
    for (int k = 0; k < 64; ++k) {
        float w = Wdt[k * 1024 + c];
#pragma unroll
        for (int r = 0; r < 32; ++r) acc[r] += ds[r][k] * w;
    }
    float bb = bdt[c];
    float tmp[32];
#pragma unroll
    for (int r = 0; r < 32; ++r) {
        float z = acc[r] + bb;
        tmp[r] = fmaxf(z, 0.f) + log1pf(expf(-fabsf(z)));
    }
    float4* dst = reinterpret_cast<float4*>(&deltaT[(size_t)c * MTOT + row0]);
#pragma unroll
    for (int q = 0; q < 8; ++q)
        dst[q] = make_float4(tmp[4 * q], tmp[4 * q + 1], tmp[4 * q + 2], tmp[4 * q + 3]);
}

// ---------------- Kernel C: chunked selective scan -> yT [d][m] ----------------
// R[t] = Rbefore[chunk] - P_local (double base, float local prefix)
// num[t] = (sum of earlier chunk partials) + local forward cumsum (recompute pass)
__global__ __launch_bounds__(256) void k_scan2(const float* __restrict__ deltaT,
                                               const float* __restrict__ xT,
                                               const float2* __restrict__ bc,
                                               const float* __restrict__ Alog,
                                               const float* __restrict__ Dp,
                                               float* __restrict__ yT) {
    __shared__ float sdelta[1024];
    __shared__ float su[1024];
    __shared__ float sy[1024];
    __shared__ double csum[16];
    __shared__ double Rbef[16];
    __shared__ float Tc[16][17];

    int d = blockIdx.x & 1023;
    int b = blockIdx.x >> 10;
    int m0 = b * 1024;
    int tid = threadIdx.x;
    int c = tid >> 4;   // chunk 0..15
    int n = tid & 15;   // state 0..15

    const float4* dsrc = reinterpret_cast<const float4*>(&deltaT[(size_t)d * MTOT + m0]);
    const float4* usrc = reinterpret_cast<const float4*>(&xT[(size_t)d * MTOT + m0]);
    reinterpret_cast<float4*>(sdelta)[tid] = dsrc[tid];
    reinterpret_cast<float4*>(su)[tid] = usrc[tid];
    __syncthreads();

    // chunk sums in double
    {
        int base = c * 64 + n * 4;
        double ps = (double)sdelta[base] + (double)sdelta[base + 1] +
                    (double)sdelta[base + 2] + (double)sdelta[base + 3];
        ps += __shfl_xor(ps, 1);
        ps += __shfl_xor(ps, 2);
        ps += __shfl_xor(ps, 4);
        ps += __shfl_xor(ps, 8);
        if (n == 0) csum[c] = ps;
    }
    __syncthreads();
    if (tid == 0) {
        double r = 0.0;
        for (int cc = 15; cc >= 0; --cc) { r += csum[cc]; Rbef[cc] = r; }
    }
    __syncthreads();

    float Af = -expf(Alog[d * NSTATE + n]);
    double Ad = (double)Af;
    double Rb = Rbef[c];
    const float2* bcp = &bc[(size_t)(m0 + c * 64) * 16 + n];

    // pass 1: chunk partial numerator sums
    float P = 0.f, T = 0.f;
    for (int tt = 0; tt < 64; ++tt) {
        float dlt = sdelta[c * 64 + tt];
        P += dlt;
        float e = __expf((float)(Ad * (Rb - (double)P)));
        float2 bcv = bcp[tt * 16];
        T += dlt * su[c * 64 + tt] * bcv.x * e;
    }
    Tc[c][n] = T;
    __syncthreads();
    float off = 0.f;
    for (int j = 0; j < c; ++j) off += Tc[j][n];

    // pass 2: recompute with running numerator, produce y
    P = 0.f;
    float num = off;
    for (int tt = 0; tt < 64; ++tt) {
        float dlt = sdelta[c * 64 + tt];
        P += dlt;
        float e = __expf((float)(Ad * (Rb - (double)P)));
        float2 bcv = bcp[tt * 16];
        num += dlt * su[c * 64 + tt] * bcv.x * e;
        float xs = num / (e + 1e-12f);
        float yv = xs * bcv.y;
        yv += __shfl_xor(yv, 1);
        yv += __shfl_xor(yv, 2);
        yv += __shfl_xor(yv, 4);
        yv += __shfl_xor(yv, 8);
        if (n == 0) sy[c * 64 + tt] = yv;
    }
    __syncthreads();
    float Dv = Dp[d];
    float4 yo = reinterpret_cast<const float4*>(sy)[tid];
    float4 uu = reinterpret_cast<const float4*>(su)[tid];
    yo.x += uu.x * Dv; yo.y += uu.y * Dv; yo.z += uu.z * Dv; yo.w += uu.w * Dv;
    reinterpret_cast<float4*>(&yT[(size_t)d * MTOT + m0])[tid] = yo;
}

// ---------------- Kernel D: out = y @ W_out + b_out (A read from yT [k][m]) ----------------
__global__ __launch_bounds__(256) void k_out(const float* __restrict__ yT,
                                             const float* __restrict__ W,
                                             const float* __restrict__ bias,
                                             float* __restrict__ out) {
    __shared__ float As[16][68];
    __shared__ float Bs[16][68];
    int bm = blockIdx.y * 64, bn = blockIdx.x * 64;
    int tid = threadIdx.x;
    int tx = tid & 15, ty = tid >> 4;
    float acc[4][4];
#pragma unroll
    for (int i = 0; i < 4; ++i)
#pragma unroll
        for (int j = 0; j < 4; ++j) acc[i][j] = 0.f;

    int ak = tid >> 4;          // 0..15 (k)
    int am4 = (tid & 15) * 4;   // 0..60 (m or n group)

    for (int k0 = 0; k0 < 1024; k0 += 16) {
        float4 av = *reinterpret_cast<const float4*>(&yT[(size_t)(k0 + ak) * MTOT + bm + am4]);
        *reinterpret_cast<float4*>(&As[ak][am4]) = av;
        float4 bv = *reinterpret_cast<const float4*>(&W[(size_t)(k0 + ak) * 1024 + bn + am4]);
        *reinterpret_cast<float4*>(&Bs[ak][am4]) = bv;
        __syncthreads();
#pragma unroll
        for (int k = 0; k < 16; ++k) {
            float4 a = *reinterpret_cast<const float4*>(&As[k][ty * 4]);
            float4 bq = *reinterpret_cast<const float4*>(&Bs[k][tx * 4]);
            acc[0][0] += a.x * bq.x; acc[0][1] += a.x * bq.y; acc[0][2] += a.x * bq.z; acc[0][3] += a.x * bq.w;
            acc[1][0] += a.y * bq.x; acc[1][1] += a.y * bq.y; acc[1][2] += a.y * bq.z; acc[1][3] += a.y * bq.w;
            acc[2][0] += a.z * bq.x; acc[2][1] += a.z * bq.y; acc[2][2] += a.z * bq.z; acc[2][3] += a.z * bq.w;
            acc[3][0] += a.w * bq.x; acc[3][1] += a.w * bq.y; acc[3][2] += a.w * bq.z; acc[3][3] += a.w * bq.w;
        }
        __syncthreads();
    }
    float4 bb = *reinterpret_cast<const float4*>(&bias[bn + tx * 4]);
#pragma unroll
    for (int i = 0; i < 4; ++i) {
        float4 o;
        o.x = acc[i][0] + bb.x;
        o.y = acc[i][1] + bb.y;
        o.z = acc[i][2] + bb.z;
        o.w = acc[i][3] + bb.w;
        *reinterpret_cast<float4*>(&out[(size_t)(bm + ty * 4 + i) * 1024 + bn + tx * 4]) = o;
    }
}

extern "C" void kernel_launch(void* const* d_in, const int* in_sizes, int n_in,
                              void* d_out, int out_size, void* d_ws, size_t ws_size,
                              hipStream_t stream) {
    const float* x    = (const float*)d_in[0];
    const float* Wx   = (const float*)d_in[1];
    const float* Wdt  = (const float*)d_in[2];
    const float* bdt  = (const float*)d_in[3];
    const float* Alog = (const float*)d_in[4];
    const float* Dp   = (const float*)d_in[5];
    const float* Wout = (const float*)d_in[6];
    const float* bout = (const float*)d_in[7];
    float* out = (float*)d_out;

    float* xdbl   = (float*)d_ws;                        // 2048*96      = 196608
    float2* bc    = (float2*)(xdbl + 2048 * 96);         // 2048*16 f2   = 65536 f
    float* deltaT = (float*)(bc + 2048 * 16);            // 1024*2048
    float* xT     = deltaT + 1024 * 2048;                // 1024*2048
    float* yT     = xT + 1024 * 2048;                    // 1024*2048

    k_xdbl<<<512, dim3(96, 4), 0, stream>>>(x, Wx, xdbl, bc);
    k_transp<<<dim3(32, 64), 256, 0, stream>>>(x, xT);
    k_delta<<<dim3(64, 4), 256, 0, stream>>>(xdbl, Wdt, bdt, deltaT);
    k_scan2<<<2048, 256, 0, stream>>>(deltaT, xT, bc, Alog, Dp, yT);
    k_out<<<dim3(16, 32), 256, 0, stream>>>(yT, Wout, bout, out);
}

// Round 3
// 144.708 us; speedup vs baseline: 2.7528x; 1.2989x over previous
//
#include <hip/hip_runtime.h>
#include <hip/hip_bf16.h>

// b=2, L=1024, d=1024, dt_rank=64, n=16, E=96
#define LSEQ 1024
#define DMODEL 1024
#define NSTATE 16
#define DTRANK 64
#define ECOL 96
#define MTOT 2048

typedef short s16x8 __attribute__((ext_vector_type(8)));
typedef float f32x4 __attribute__((ext_vector_type(4)));

__device__ inline unsigned short f2bf(float f) {
    unsigned int u = __builtin_bit_cast(unsigned int, f);
    u += 0x7FFFu + ((u >> 16) & 1u);
    return (unsigned short)(u >> 16);
}

// ---------------- Kernel A: x_dbl = x @ W_x  (2048 x 96, K=1024) + packed BC ----------------
__global__ __launch_bounds__(384) void k_xdbl(const float* __restrict__ x,
                                              const float* __restrict__ Wx,
                                              float* __restrict__ xdbl,
                                              float2* __restrict__ bc) {
    __shared__ float xs[4][1024];
    __shared__ float sacc[4][96];
    int r0 = blockIdx.x * 4;
    int tid = threadIdx.y * 96 + threadIdx.x;  // 0..383
    for (int i = tid; i < 4 * 1024; i += 384) {
        int rr = i >> 10, kk = i & 1023;
        xs[rr][kk] = x[(size_t)(r0 + rr) * 1024 + kk];
    }
    __syncthreads();
    int e = threadIdx.x;   // 0..95
    int r = threadIdx.y;   // 0..3
    float acc = 0.f;
    for (int k = 0; k < 1024; k += 4) {
        acc += xs[r][k + 0] * Wx[(k + 0) * 96 + e];
        acc += xs[r][k + 1] * Wx[(k + 1) * 96 + e];
        acc += xs[r][k + 2] * Wx[(k + 2) * 96 + e];
        acc += xs[r][k + 3] * Wx[(k + 3) * 96 + e];
    }
    xdbl[(size_t)(r0 + r) * 96 + e] = acc;
    sacc[r][e] = acc;
    __syncthreads();
    if (tid < 64) {
        int rr = tid >> 4, n = tid & 15;
        bc[(size_t)(r0 + rr) * 16 + n] = make_float2(sacc[rr][64 + n], sacc[rr][80 + n]);
    }
}

// ---------------- Transpose x [2048][1024] -> xT [1024][2048] ----------------
__global__ __launch_bounds__(256) void k_transp(const float* __restrict__ in,
                                                float* __restrict__ out) {
    __shared__ float tile[32][33];
    int x0 = blockIdx.x * 32;  // d
    int y0 = blockIdx.y * 32;  // m
    int tx = threadIdx.x & 31, ty = threadIdx.x >> 5;  // ty 0..7
#pragma unroll
    for (int j = 0; j < 32; j += 8)
        tile[ty + j][tx] = in[(size_t)(y0 + ty + j) * 1024 + x0 + tx];
    __syncthreads();
#pragma unroll
    for (int j = 0; j < 32; j += 8)
        out[(size_t)(x0 + ty + j) * 2048 + y0 + tx] = tile[tx][ty + j];
}

// -------- Kernel B: deltaT[d][m] = softplus(x_dbl[:, :64] @ W_dt + b_dt)^T --------
__global__ __launch_bounds__(256) void k_delta(const float* __restrict__ xdbl,
                                               const float* __restrict__ Wdt,
                                               const float* __restrict__ bdt,
                                               float* __restrict__ deltaT) {
    __shared__ float ds[32][64];
    int row0 = blockIdx.x * 32;
    int col0 = blockIdx.y * 256;
    int tid = threadIdx.x;
    for (int i = tid; i < 32 * 64; i += 256) {
        int rr = i >> 6, kk = i & 63;
        ds[rr][kk] = xdbl[(size_t)(row0 + rr) * 96 + kk];
    }
    __syncthreads();
    int c = col0 + tid;  // d index
    float acc[32];
#pragma unroll
    for (int r = 0; r < 32; ++r) acc[r] = 0.f;
    for (int k = 0; k < 64; ++k) {
        float w = Wdt[k * 1024 + c];
#pragma unroll
        for (int r = 0; r < 32; ++r) acc[r] += ds[r][k] * w;
    }
    float bb = bdt[c];
    float tmp[32];
#pragma unroll
    for (int r = 0; r < 32; ++r) {
        float z = acc[r] + bb;
        tmp[r] = fmaxf(z, 0.f) + log1pf(expf(-fabsf(z)));
    }
    float4* dst = reinterpret_cast<float4*>(&deltaT[(size_t)c * MTOT + row0]);
#pragma unroll
    for (int q = 0; q < 8; ++q)
        dst[q] = make_float4(tmp[4 * q], tmp[4 * q + 1], tmp[4 * q + 2], tmp[4 * q + 3]);
}

// ---------------- Kernel C: chunked selective scan -> yT bf16 [d][m] ----------------
__global__ __launch_bounds__(256) void k_scan2(const float* __restrict__ deltaT,
                                               const float* __restrict__ xT,
                                               const float2* __restrict__ bc,
                                               const float* __restrict__ Alog,
                                               const float* __restrict__ Dp,
                                               unsigned short* __restrict__ yTbf) {
    __shared__ float sdelta[1024];
    __shared__ float su[1024];
    __shared__ float sy[1024];
    __shared__ double csum[16];
    __shared__ double Rbef[16];
    __shared__ float Tc[16][17];

    int d = blockIdx.x & 1023;
    int b = blockIdx.x >> 10;
    int m0 = b * 1024;
    int tid = threadIdx.x;
    int c = tid >> 4;   // chunk 0..15
    int n = tid & 15;   // state 0..15

    const float4* dsrc = reinterpret_cast<const float4*>(&deltaT[(size_t)d * MTOT + m0]);
    const float4* usrc = reinterpret_cast<const float4*>(&xT[(size_t)d * MTOT + m0]);
    reinterpret_cast<float4*>(sdelta)[tid] = dsrc[tid];
    reinterpret_cast<float4*>(su)[tid] = usrc[tid];
    __syncthreads();

    // chunk sums in double
    {
        int base = c * 64 + n * 4;
        double ps = (double)sdelta[base] + (double)sdelta[base + 1] +
                    (double)sdelta[base + 2] + (double)sdelta[base + 3];
        ps += __shfl_xor(ps, 1);
        ps += __shfl_xor(ps, 2);
        ps += __shfl_xor(ps, 4);
        ps += __shfl_xor(ps, 8);
        if (n == 0) csum[c] = ps;
    }
    __syncthreads();
    if (tid == 0) {
        double r = 0.0;
        for (int cc = 15; cc >= 0; --cc) { r += csum[cc]; Rbef[cc] = r; }
    }
    __syncthreads();

    float Af = -expf(Alog[d * NSTATE + n]);
    double Ad = (double)Af;
    double Rb = Rbef[c];
    const float2* bcp = &bc[(size_t)(m0 + c * 64) * 16 + n];

    // pass 1: chunk partial numerator sums
    float P = 0.f, T = 0.f;
    for (int tt = 0; tt < 64; ++tt) {
        float dlt = sdelta[c * 64 + tt];
        P += dlt;
        float e = __expf((float)(Ad * (Rb - (double)P)));
        float2 bcv = bcp[tt * 16];
        T += dlt * su[c * 64 + tt] * bcv.x * e;
    }
    Tc[c][n] = T;
    __syncthreads();
    float off = 0.f;
    for (int j = 0; j < c; ++j) off += Tc[j][n];

    // pass 2: recompute with running numerator, produce y
    P = 0.f;
    float num = off;
    for (int tt = 0; tt < 64; ++tt) {
        float dlt = sdelta[c * 64 + tt];
        P += dlt;
        float e = __expf((float)(Ad * (Rb - (double)P)));
        float2 bcv = bcp[tt * 16];
        num += dlt * su[c * 64 + tt] * bcv.x * e;
        float xs = num / (e + 1e-12f);
        float yv = xs * bcv.y;
        yv += __shfl_xor(yv, 1);
        yv += __shfl_xor(yv, 2);
        yv += __shfl_xor(yv, 4);
        yv += __shfl_xor(yv, 8);
        if (n == 0) sy[c * 64 + tt] = yv;
    }
    __syncthreads();
    float Dv = Dp[d];
    float4 yo = reinterpret_cast<const float4*>(sy)[tid];
    float4 uu = reinterpret_cast<const float4*>(su)[tid];
    ushort4 o;
    o.x = f2bf(yo.x + uu.x * Dv);
    o.y = f2bf(yo.y + uu.y * Dv);
    o.z = f2bf(yo.z + uu.z * Dv);
    o.w = f2bf(yo.w + uu.w * Dv);
    reinterpret_cast<ushort4*>(&yTbf[(size_t)d * MTOT + m0])[tid] = o;
}

// ---------------- W_out [k][e] f32 -> WbfT [e][k] bf16 ----------------
__global__ __launch_bounds__(256) void k_wconv(const float* __restrict__ W,
                                               unsigned short* __restrict__ WT) {
    __shared__ float t[64][65];
    int k0 = blockIdx.y * 64, e0 = blockIdx.x * 64;
    int tx = threadIdx.x & 63, ty = threadIdx.x >> 6;
#pragma unroll
    for (int j = 0; j < 64; j += 4)
        t[ty + j][tx] = W[(size_t)(k0 + ty + j) * 1024 + e0 + tx];
    __syncthreads();
#pragma unroll
    for (int j = 0; j < 64; j += 4)
        WT[(size_t)(e0 + ty + j) * 1024 + k0 + tx] = f2bf(t[tx][ty + j]);
}

// ---------------- yTbf [d][m] bf16 -> ybf [m][d] bf16 ----------------
__global__ __launch_bounds__(256) void k_ytr(const unsigned short* __restrict__ in,
                                             unsigned short* __restrict__ out) {
    __shared__ unsigned short t[64][66];
    int d0 = blockIdx.y * 64, m0 = blockIdx.x * 64;
    int tx = threadIdx.x & 63, ty = threadIdx.x >> 6;
#pragma unroll
    for (int j = 0; j < 64; j += 4)
        t[ty + j][tx] = in[(size_t)(d0 + ty + j) * MTOT + m0 + tx];
    __syncthreads();
#pragma unroll
    for (int j = 0; j < 64; j += 4)
        out[(size_t)(m0 + ty + j) * 1024 + d0 + tx] = t[tx][ty + j];
}

// ---------------- Kernel D: out = ybf @ WbfT^T + b_out via MFMA ----------------
// A: ybf [M=2048][K=1024] bf16 row-major (k-contig)
// B: WbfT [N=1024][K=1024] bf16 row-major (k-contig)  (= W_out^T)
__global__ __launch_bounds__(256) void k_gemm(const unsigned short* __restrict__ A,
                                              const unsigned short* __restrict__ B,
                                              const float* __restrict__ bias,
                                              float* __restrict__ out) {
    __shared__ unsigned short As[128 * 64];  // [row][k] linear
    __shared__ unsigned short Bs[64 * 64];
    const int GN = 1024, GK = 1024;
    int bm = blockIdx.y * 128;
    int bn = blockIdx.x * 64;
    int tid = threadIdx.x;
    int lane = tid & 63;
    int w = tid >> 6;        // wave 0..3
    int wm = w >> 1, wn = w & 1;
    int r = lane & 15, kb = lane >> 4;

    f32x4 zero4 = {0.f, 0.f, 0.f, 0.f};
    f32x4 acc[4][2];
#pragma unroll
    for (int mf = 0; mf < 4; ++mf)
#pragma unroll
        for (int nf = 0; nf < 2; ++nf) acc[mf][nf] = zero4;

    s16x8 ra[4], rb[2];
    auto stage_load = [&](int k0) {
#pragma unroll
        for (int i = 0; i < 4; ++i) {
            int q = tid + i * 256;
            ra[i] = *reinterpret_cast<const s16x8*>(&A[(size_t)(bm + (q >> 3)) * GK + k0 + (q & 7) * 8]);
        }
#pragma unroll
        for (int i = 0; i < 2; ++i) {
            int q = tid + i * 256;
            rb[i] = *reinterpret_cast<const s16x8*>(&B[(size_t)(bn + (q >> 3)) * GK + k0 + (q & 7) * 8]);
        }
    };

    stage_load(0);
    for (int k0 = 0; k0 < GK; k0 += 64) {
        __syncthreads();
#pragma unroll
        for (int i = 0; i < 4; ++i)
            *reinterpret_cast<s16x8*>(&As[(tid + i * 256) * 8]) = ra[i];
#pragma unroll
        for (int i = 0; i < 2; ++i)
            *reinterpret_cast<s16x8*>(&Bs[(tid + i * 256) * 8]) = rb[i];
        __syncthreads();
        if (k0 + 64 < GK) stage_load(k0 + 64);
#pragma unroll
        for (int ks = 0; ks < 2; ++ks) {
            s16x8 af[4], bfr[2];
#pragma unroll
            for (int mf = 0; mf < 4; ++mf)
                af[mf] = *reinterpret_cast<const s16x8*>(&As[(wm * 64 + mf * 16 + r) * 64 + ks * 32 + kb * 8]);
#pragma unroll
            for (int nf = 0; nf < 2; ++nf)
                bfr[nf] = *reinterpret_cast<const s16x8*>(&Bs[(wn * 32 + nf * 16 + r) * 64 + ks * 32 + kb * 8]);
#pragma unroll
            for (int mf = 0; mf < 4; ++mf)
#pragma unroll
                for (int nf = 0; nf < 2; ++nf)
                    acc[mf][nf] = __builtin_amdgcn_mfma_f32_16x16x32_bf16(af[mf], bfr[nf], acc[mf][nf], 0, 0, 0);
        }
    }
#pragma unroll
    for (int nf = 0; nf < 2; ++nf) {
        float bb = bias[bn + wn * 32 + nf * 16 + r];
#pragma unroll
        for (int mf = 0; mf < 4; ++mf)
#pragma unroll
            for (int j = 0; j < 4; ++j)
                out[(size_t)(bm + wm * 64 + mf * 16 + kb * 4 + j) * GN + bn + wn * 32 + nf * 16 + r] =
                    acc[mf][nf][j] + bb;
    }
}

extern "C" void kernel_launch(void* const* d_in, const int* in_sizes, int n_in,
                              void* d_out, int out_size, void* d_ws, size_t ws_size,
                              hipStream_t stream) {
    const float* x    = (const float*)d_in[0];
    const float* Wx   = (const float*)d_in[1];
    const float* Wdt  = (const float*)d_in[2];
    const float* bdt  = (const float*)d_in[3];
    const float* Alog = (const float*)d_in[4];
    const float* Dp   = (const float*)d_in[5];
    const float* Wout = (const float*)d_in[6];
    const float* bout = (const float*)d_in[7];
    float* out = (float*)d_out;

    float* xdbl   = (float*)d_ws;                          // 2048*96 f
    float2* bc    = (float2*)(xdbl + 2048 * 96);           // 2048*16 f2
    float* deltaT = (float*)(bc + 2048 * 16);              // 1024*2048 f
    float* xT     = deltaT + 1024 * 2048;                  // 1024*2048 f
    unsigned short* yTbf = (unsigned short*)(xT + 1024 * 2048);  // 1024*2048 bf16
    unsigned short* ybf  = yTbf + 1024 * 2048;             // 2048*1024 bf16
    unsigned short* WbfT = ybf + 2048 * 1024;              // 1024*1024 bf16

    k_xdbl<<<512, dim3(96, 4), 0, stream>>>(x, Wx, xdbl, bc);
    k_transp<<<dim3(32, 64), 256, 0, stream>>>(x, xT);
    k_delta<<<dim3(64, 4), 256, 0, stream>>>(xdbl, Wdt, bdt, deltaT);
    k_wconv<<<dim3(16, 16), 256, 0, stream>>>(Wout, WbfT);
    k_scan2<<<2048, 256, 0, stream>>>(deltaT, xT, bc, Alog, Dp, yTbf);
    k_ytr<<<dim3(32, 16), 256, 0, stream>>>(yTbf, ybf);
    k_gemm<<<dim3(16, 16), 256, 0, stream>>>(ybf, WbfT, bout, out);
}

// Round 4
// 115.771 us; speedup vs baseline: 3.4409x; 1.2500x over previous
//
#include <hip/hip_runtime.h>
#include <hip/hip_bf16.h>

// b=2, L=1024, d=1024, dt_rank=64, n=16, E=96
#define LSEQ 1024
#define DMODEL 1024
#define NSTATE 16
#define DTRANK 64
#define ECOL 96
#define MTOT 2048

typedef short s16x8 __attribute__((ext_vector_type(8)));
typedef float f32x4 __attribute__((ext_vector_type(4)));

__device__ inline unsigned short f2bf(float f) {
    unsigned int u = __builtin_bit_cast(unsigned int, f);
    u += 0x7FFFu + ((u >> 16) & 1u);
    return (unsigned short)(u >> 16);
}

__device__ inline f32x4 shflup4(f32x4 v, int off) {
    f32x4 r;
    r[0] = __shfl_up(v[0], off, 64);
    r[1] = __shfl_up(v[1], off, 64);
    r[2] = __shfl_up(v[2], off, 64);
    r[3] = __shfl_up(v[3], off, 64);
    return r;
}

// ---------------- Kernel A: x_dbl = x @ W_x  (2048 x 96, K=1024) + packed B/C ----------------
__global__ __launch_bounds__(384) void k_xdbl(const float* __restrict__ x,
                                              const float* __restrict__ Wx,
                                              float* __restrict__ xdbl,
                                              float* __restrict__ bpk,
                                              float* __restrict__ cpk) {
    __shared__ float xs[4][1024];
    __shared__ float sacc[4][96];
    int r0 = blockIdx.x * 4;
    int tid = threadIdx.y * 96 + threadIdx.x;  // 0..383
    for (int i = tid; i < 4 * 1024; i += 384) {
        int rr = i >> 10, kk = i & 1023;
        xs[rr][kk] = x[(size_t)(r0 + rr) * 1024 + kk];
    }
    __syncthreads();
    int e = threadIdx.x;   // 0..95
    int r = threadIdx.y;   // 0..3
    float acc = 0.f;
    for (int k = 0; k < 1024; k += 4) {
        acc += xs[r][k + 0] * Wx[(k + 0) * 96 + e];
        acc += xs[r][k + 1] * Wx[(k + 1) * 96 + e];
        acc += xs[r][k + 2] * Wx[(k + 2) * 96 + e];
        acc += xs[r][k + 3] * Wx[(k + 3) * 96 + e];
    }
    xdbl[(size_t)(r0 + r) * 96 + e] = acc;
    sacc[r][e] = acc;
    __syncthreads();
    if (tid < 64) {
        int rr = tid >> 4, n = tid & 15;
        bpk[(size_t)(r0 + rr) * 16 + n] = sacc[rr][64 + n];
        cpk[(size_t)(r0 + rr) * 16 + n] = sacc[rr][80 + n];
    }
}

// ---------------- Transpose x [2048][1024] -> xT [1024][2048] ----------------
__global__ __launch_bounds__(256) void k_transp(const float* __restrict__ in,
                                                float* __restrict__ out) {
    __shared__ float tile[32][33];
    int x0 = blockIdx.x * 32;  // d
    int y0 = blockIdx.y * 32;  // m
    int tx = threadIdx.x & 31, ty = threadIdx.x >> 5;  // ty 0..7
#pragma unroll
    for (int j = 0; j < 32; j += 8)
        tile[ty + j][tx] = in[(size_t)(y0 + ty + j) * 1024 + x0 + tx];
    __syncthreads();
#pragma unroll
    for (int j = 0; j < 32; j += 8)
        out[(size_t)(x0 + ty + j) * 2048 + y0 + tx] = tile[tx][ty + j];
}

// -------- Kernel B: deltaT[d][m] = softplus(x_dbl[:, :64] @ W_dt + b_dt)^T --------
__global__ __launch_bounds__(256) void k_delta(const float* __restrict__ xdbl,
                                               const float* __restrict__ Wdt,
                                               const float* __restrict__ bdt,
                                               float* __restrict__ deltaT) {
    __shared__ float ds[32][64];
    int row0 = blockIdx.x * 32;
    int col0 = blockIdx.y * 256;
    int tid = threadIdx.x;
    for (int i = tid; i < 32 * 64; i += 256) {
        int rr = i >> 6, kk = i & 63;
        ds[rr][kk] = xdbl[(size_t)(row0 + rr) * 96 + kk];
    }
    __syncthreads();
    int c = col0 + tid;  // d index
    float acc[32];
#pragma unroll
    for (int r = 0; r < 32; ++r) acc[r] = 0.f;
    for (int k = 0; k < 64; ++k) {
        float w = Wdt[k * 1024 + c];
#pragma unroll
        for (int r = 0; r < 32; ++r) acc[r] += ds[r][k] * w;
    }
    float bb = bdt[c];
    float tmp[32];
#pragma unroll
    for (int r = 0; r < 32; ++r) {
        float z = acc[r] + bb;
        tmp[r] = fmaxf(z, 0.f) + log1pf(expf(-fabsf(z)));
    }
    float4* dst = reinterpret_cast<float4*>(&deltaT[(size_t)c * MTOT + row0]);
#pragma unroll
    for (int q = 0; q < 8; ++q)
        dst[q] = make_float4(tmp[4 * q], tmp[4 * q + 1], tmp[4 * q + 2], tmp[4 * q + 3]);
}

// ---------------- Kernel C: chunked selective scan -> yT bf16 [d][m] ----------------
// 64 chunks x 16 steps; thread quad (l=0..3) covers n-groups of 4.
// R[t] = Rbef[c] - P_local;  exponent: arg = Sb - A*P,  Sb = (f32)(A * Rbef) (f64 once)
__global__ __launch_bounds__(256) void k_scan3(const float* __restrict__ deltaT,
                                               const float* __restrict__ xT,
                                               const float* __restrict__ bpk,
                                               const float* __restrict__ cpk,
                                               const float* __restrict__ Alog,
                                               const float* __restrict__ Dp,
                                               unsigned short* __restrict__ yTbf) {
    __shared__ double csum[64];
    __shared__ double Rbef[64];
    __shared__ float TcL[64 * 20];   // padded rows of 20 -> conflict-light
    __shared__ float syp[64 * 17];   // padded rows of 17 -> conflict-free

    int tid = threadIdx.x;
    int c = tid >> 2, l = tid & 3;
    int w = tid >> 6, lane = tid & 63;
    int d = blockIdx.x & 1023, b = blockIdx.x >> 10;
    int m0 = b * 1024;

    const f32x4* dp = (const f32x4*)(deltaT + (size_t)d * MTOT + m0 + c * 16);
    const f32x4* up = (const f32x4*)(xT + (size_t)d * MTOT + m0 + c * 16);
    const f32x4* Bp = (const f32x4*)bpk + (size_t)(m0 + c * 16) * 4 + l;
    const f32x4* Cp = (const f32x4*)cpk + (size_t)(m0 + c * 16) * 4 + l;

    // chunk delta sum (double)
    double dsum = 0.0;
#pragma unroll
    for (int i = 0; i < 4; ++i) {
        f32x4 v = dp[i];
        dsum += (double)v[0] + (double)v[1] + (double)v[2] + (double)v[3];
    }
    if (l == 0) csum[c] = dsum;
    __syncthreads();
    // inclusive suffix sum over 64 chunks (wave 0, Kogge-Stone)
    if (tid < 64) {
        double v = csum[tid];
#pragma unroll
        for (int off = 1; off < 64; off <<= 1) {
            double t = __shfl_down(v, off, 64);
            if (tid + off < 64) v += t;
        }
        Rbef[tid] = v;
    }
    __syncthreads();

    float Af[4], Sb[4];
    double Rb = Rbef[c];
#pragma unroll
    for (int j = 0; j < 4; ++j) {
        Af[j] = -__expf(Alog[d * NSTATE + 4 * l + j]);
        Sb[j] = (float)((double)Af[j] * Rb);
    }
    float Dv = Dp[d];

    // ---- pass 1: chunk-partial numerator sums Tn[n] ----
    float P = 0.f;
    f32x4 Tn = {0.f, 0.f, 0.f, 0.f};
#pragma unroll 1
    for (int t4 = 0; t4 < 4; ++t4) {
        f32x4 rdv = dp[t4];
        f32x4 ruv = up[t4];
        f32x4 Bq0 = Bp[(t4 * 4 + 0) * 4];
        f32x4 Bq1 = Bp[(t4 * 4 + 1) * 4];
        f32x4 Bq2 = Bp[(t4 * 4 + 2) * 4];
        f32x4 Bq3 = Bp[(t4 * 4 + 3) * 4];
        f32x4 Bq[4] = {Bq0, Bq1, Bq2, Bq3};
#pragma unroll
        for (int k = 0; k < 4; ++k) {
            float dlt = rdv[k];
            P += dlt;
            float du = dlt * ruv[k];
#pragma unroll
            for (int j = 0; j < 4; ++j) {
                float e = __expf(fmaf(-Af[j], P, Sb[j]));
                Tn[j] = fmaf(du * Bq[k][j], e, Tn[j]);
            }
        }
    }
    *(f32x4*)&TcL[c * 20 + 4 * l] = Tn;
    __syncthreads();

    // ---- exclusive prefix of Tc over chunks, per n (wave w owns n-group w) ----
    {
        f32x4 v = *(const f32x4*)&TcL[lane * 20 + 4 * w];
#pragma unroll
        for (int off = 1; off < 64; off <<= 1) {
            f32x4 t = shflup4(v, off);
            if (lane >= off) v += t;
        }
        f32x4 ex = shflup4(v, 1);
        if (lane == 0) ex = (f32x4){0.f, 0.f, 0.f, 0.f};
        *(f32x4*)&TcL[lane * 20 + 4 * w] = ex;
    }
    __syncthreads();
    f32x4 num = *(const f32x4*)&TcL[c * 20 + 4 * l];

    // ---- pass 2: full scan with running numerator ----
    P = 0.f;
#pragma unroll 1
    for (int t4 = 0; t4 < 4; ++t4) {
        f32x4 rdv = dp[t4];
        f32x4 ruv = up[t4];
        f32x4 Bq[4], Cq[4];
#pragma unroll
        for (int k = 0; k < 4; ++k) {
            Bq[k] = Bp[(t4 * 4 + k) * 4];
            Cq[k] = Cp[(t4 * 4 + k) * 4];
        }
#pragma unroll
        for (int k = 0; k < 4; ++k) {
            float dlt = rdv[k];
            P += dlt;
            float du = dlt * ruv[k];
            float psum = 0.f;
#pragma unroll
            for (int j = 0; j < 4; ++j) {
                float e = __expf(fmaf(-Af[j], P, Sb[j]));
                num[j] = fmaf(du * Bq[k][j], e, num[j]);
                float r = __builtin_amdgcn_rcpf(e + 1e-12f);
                psum = fmaf(num[j] * r, Cq[k][j], psum);
            }
            psum += __shfl_xor(psum, 1);
            psum += __shfl_xor(psum, 2);
            if (l == 0) syp[c * 17 + t4 * 4 + k] = fmaf(ruv[k], Dv, psum);
        }
    }
    __syncthreads();
    // ---- output: bf16 convert + coalesced write ----
    {
        int cc = tid >> 2, oo = (tid & 3) * 4;
        const float* sp = &syp[cc * 17 + oo];
        ushort4 o;
        o.x = f2bf(sp[0]);
        o.y = f2bf(sp[1]);
        o.z = f2bf(sp[2]);
        o.w = f2bf(sp[3]);
        *reinterpret_cast<ushort4*>(&yTbf[(size_t)d * MTOT + m0 + tid * 4]) = o;
    }
}

// ---------------- W_out [k][e] f32 -> WbfT [e][k] bf16 ----------------
__global__ __launch_bounds__(256) void k_wconv(const float* __restrict__ W,
                                               unsigned short* __restrict__ WT) {
    __shared__ float t[64][65];
    int k0 = blockIdx.y * 64, e0 = blockIdx.x * 64;
    int tx = threadIdx.x & 63, ty = threadIdx.x >> 6;
#pragma unroll
    for (int j = 0; j < 64; j += 4)
        t[ty + j][tx] = W[(size_t)(k0 + ty + j) * 1024 + e0 + tx];
    __syncthreads();
#pragma unroll
    for (int j = 0; j < 64; j += 4)
        WT[(size_t)(e0 + ty + j) * 1024 + k0 + tx] = f2bf(t[tx][ty + j]);
}

// ---------------- yTbf [d][m] bf16 -> ybf [m][d] bf16 ----------------
__global__ __launch_bounds__(256) void k_ytr(const unsigned short* __restrict__ in,
                                             unsigned short* __restrict__ out) {
    __shared__ unsigned short t[64][66];
    int d0 = blockIdx.y * 64, m0 = blockIdx.x * 64;
    int tx = threadIdx.x & 63, ty = threadIdx.x >> 6;
#pragma unroll
    for (int j = 0; j < 64; j += 4)
        t[ty + j][tx] = in[(size_t)(d0 + ty + j) * MTOT + m0 + tx];
    __syncthreads();
#pragma unroll
    for (int j = 0; j < 64; j += 4)
        out[(size_t)(m0 + ty + j) * 1024 + d0 + tx] = t[tx][ty + j];
}

// ---------------- Kernel D: out = ybf @ WbfT^T + b_out via MFMA ----------------
__global__ __launch_bounds__(256) void k_gemm(const unsigned short* __restrict__ A,
                                              const unsigned short* __restrict__ B,
                                              const float* __restrict__ bias,
                                              float* __restrict__ out) {
    __shared__ unsigned short As[128 * 64];  // [row][k] linear
    __shared__ unsigned short Bs[64 * 64];
    const int GN = 1024, GK = 1024;
    int bm = blockIdx.y * 128;
    int bn = blockIdx.x * 64;
    int tid = threadIdx.x;
    int lane = tid & 63;
    int w = tid >> 6;        // wave 0..3
    int wm = w >> 1, wn = w & 1;
    int r = lane & 15, kb = lane >> 4;

    f32x4 zero4 = {0.f, 0.f, 0.f, 0.f};
    f32x4 acc[4][2];
#pragma unroll
    for (int mf = 0; mf < 4; ++mf)
#pragma unroll
        for (int nf = 0; nf < 2; ++nf) acc[mf][nf] = zero4;

    s16x8 ra[4], rb[2];
    auto stage_load = [&](int k0) {
#pragma unroll
        for (int i = 0; i < 4; ++i) {
            int q = tid + i * 256;
            ra[i] = *reinterpret_cast<const s16x8*>(&A[(size_t)(bm + (q >> 3)) * GK + k0 + (q & 7) * 8]);
        }
#pragma unroll
        for (int i = 0; i < 2; ++i) {
            int q = tid + i * 256;
            rb[i] = *reinterpret_cast<const s16x8*>(&B[(size_t)(bn + (q >> 3)) * GK + k0 + (q & 7) * 8]);
        }
    };

    stage_load(0);
    for (int k0 = 0; k0 < GK; k0 += 64) {
        __syncthreads();
#pragma unroll
        for (int i = 0; i < 4; ++i)
            *reinterpret_cast<s16x8*>(&As[(tid + i * 256) * 8]) = ra[i];
#pragma unroll
        for (int i = 0; i < 2; ++i)
            *reinterpret_cast<s16x8*>(&Bs[(tid + i * 256) * 8]) = rb[i];
        __syncthreads();
        if (k0 + 64 < GK) stage_load(k0 + 64);
#pragma unroll
        for (int ks = 0; ks < 2; ++ks) {
            s16x8 af[4], bfr[2];
#pragma unroll
            for (int mf = 0; mf < 4; ++mf)
                af[mf] = *reinterpret_cast<const s16x8*>(&As[(wm * 64 + mf * 16 + r) * 64 + ks * 32 + kb * 8]);
#pragma unroll
            for (int nf = 0; nf < 2; ++nf)
                bfr[nf] = *reinterpret_cast<const s16x8*>(&Bs[(wn * 32 + nf * 16 + r) * 64 + ks * 32 + kb * 8]);
#pragma unroll
            for (int mf = 0; mf < 4; ++mf)
#pragma unroll
                for (int nf = 0; nf < 2; ++nf)
                    acc[mf][nf] = __builtin_amdgcn_mfma_f32_16x16x32_bf16(af[mf], bfr[nf], acc[mf][nf], 0, 0, 0);
        }
    }
#pragma unroll
    for (int nf = 0; nf < 2; ++nf) {
        float bb = bias[bn + wn * 32 + nf * 16 + r];
#pragma unroll
        for (int mf = 0; mf < 4; ++mf)
#pragma unroll
            for (int j = 0; j < 4; ++j)
                out[(size_t)(bm + wm * 64 + mf * 16 + kb * 4 + j) * GN + bn + wn * 32 + nf * 16 + r] =
                    acc[mf][nf][j] + bb;
    }
}

extern "C" void kernel_launch(void* const* d_in, const int* in_sizes, int n_in,
                              void* d_out, int out_size, void* d_ws, size_t ws_size,
                              hipStream_t stream) {
    const float* x    = (const float*)d_in[0];
    const float* Wx   = (const float*)d_in[1];
    const float* Wdt  = (const float*)d_in[2];
    const float* bdt  = (const float*)d_in[3];
    const float* Alog = (const float*)d_in[4];
    const float* Dp   = (const float*)d_in[5];
    const float* Wout = (const float*)d_in[6];
    const float* bout = (const float*)d_in[7];
    float* out = (float*)d_out;

    float* xdbl   = (float*)d_ws;                          // 2048*96 f
    float* bpk    = xdbl + 2048 * 96;                      // 2048*16 f
    float* cpk    = bpk + 2048 * 16;                       // 2048*16 f
    float* deltaT = cpk + 2048 * 16;                       // 1024*2048 f
    float* xT     = deltaT + 1024 * 2048;                  // 1024*2048 f
    unsigned short* yTbf = (unsigned short*)(xT + 1024 * 2048);  // 1024*2048 bf16
    unsigned short* ybf  = yTbf + 1024 * 2048;             // 2048*1024 bf16
    unsigned short* WbfT = ybf + 2048 * 1024;              // 1024*1024 bf16

    k_xdbl<<<512, dim3(96, 4), 0, stream>>>(x, Wx, xdbl, bpk, cpk);
    k_transp<<<dim3(32, 64), 256, 0, stream>>>(x, xT);
    k_delta<<<dim3(64, 4), 256, 0, stream>>>(xdbl, Wdt, bdt, deltaT);
    k_wconv<<<dim3(16, 16), 256, 0, stream>>>(Wout, WbfT);
    k_scan3<<<2048, 256, 0, stream>>>(deltaT, xT, bpk, cpk, Alog, Dp, yTbf);
    k_ytr<<<dim3(32, 16), 256, 0, stream>>>(yTbf, ybf);
    k_gemm<<<dim3(16, 16), 256, 0, stream>>>(ybf, WbfT, bout, out);
}